// Round 1
// baseline (1682.627 us; speedup 1.0000x reference)
//
#include <hip/hip_runtime.h>

// Problem constants (fixed by setup_inputs)
#define N_   32
#define C_   512
#define CM_  128
#define H_   48
#define W_   48
#define HW_  (H_*W_)
#define P_   512

// ---------------------------------------------------------------------------
// Kernel 1: per-(n,c) plane: mean over 48x48 and 3x3 adaptive max pool (16x16
// regions). One 256-thread block per plane; thread t reads element t of each
// of the nine 16x16 regions. Wave shuffle reduce, then cross-wave via LDS.
// ---------------------------------------------------------------------------
__global__ __launch_bounds__(256) void pool_kernel(const float* __restrict__ x,
                                                   float* __restrict__ meanx,
                                                   float* __restrict__ xm) {
    int plane = blockIdx.x;                 // n*C + c
    const float* base = x + (size_t)plane * HW_;
    int t = threadIdx.x;
    int r = t >> 4, cc = t & 15;            // position within 16x16 region
    float sum = 0.f;
    float mx[9];
#pragma unroll
    for (int b = 0; b < 9; ++b) {
        int h = (b / 3) * 16 + r;
        int w = (b % 3) * 16 + cc;
        float v = base[h * W_ + w];
        mx[b] = v;
        sum += v;
    }
    // wave (64-lane) reduction
#pragma unroll
    for (int off = 32; off > 0; off >>= 1) {
        sum += __shfl_down(sum, off);
#pragma unroll
        for (int b = 0; b < 9; ++b) mx[b] = fmaxf(mx[b], __shfl_down(mx[b], off));
    }
    __shared__ float s[4][10];
    int wave = t >> 6, lane = t & 63;
    if (lane == 0) {
#pragma unroll
        for (int b = 0; b < 9; ++b) s[wave][b] = mx[b];
        s[wave][9] = sum;
    }
    __syncthreads();
    if (t < 9) {
        float v = fmaxf(fmaxf(s[0][t], s[1][t]), fmaxf(s[2][t], s[3][t]));
        xm[(size_t)plane * 9 + t] = v;
    } else if (t == 9) {
        float v = s[0][9] + s[1][9] + s[2][9] + s[3][9];
        meanx[plane] = v * (1.0f / (float)HW_);
    }
}

// ---------------------------------------------------------------------------
// Kernel 2: per-sample branch math. Block = one n, 128 threads (one per o).
// Computes acc[j] = sum_c Wc[o][c] * in[c][j] where in[c][0..8]=xm, in[c][9]=mean.
// Emits gs[n][o][0][b] = g_kern, gs[n][o][1][b] = sk.
// ---------------------------------------------------------------------------
__global__ __launch_bounds__(128) void branch_kernel(const float* __restrict__ meanx,
                                                     const float* __restrict__ xm,
                                                     const float* __restrict__ Wc,
                                                     const float* __restrict__ bc,
                                                     const float* __restrict__ Wkk,
                                                     const float* __restrict__ bkk,
                                                     float* __restrict__ gs) {
    int n = blockIdx.x;
    __shared__ float sin_[C_ * 10];
    int t = threadIdx.x;
    for (int i = t; i < C_ * 10; i += 128) {
        int c = i / 10, j = i % 10;
        sin_[i] = (j < 9) ? xm[((size_t)n * C_ + c) * 9 + j] : meanx[n * C_ + c];
    }
    __syncthreads();
    int o = t;
    float acc[10];
#pragma unroll
    for (int j = 0; j < 10; ++j) acc[j] = 0.f;
    const float* wrow = Wc + (size_t)o * C_;
    for (int c = 0; c < C_; ++c) {
        float wv = wrow[c];
        const float* in = &sin_[c * 10];
#pragma unroll
        for (int j = 0; j < 10; ++j) acc[j] += wv * in[j];
    }
    float bco = bc[o];
    float gk1 = fmaxf(acc[9] + bco, 0.f);
    size_t gbase = ((size_t)n * CM_ + o) * 18;
#pragma unroll
    for (int b = 0; b < 9; ++b) {
        gs[gbase + b]     = gk1 * Wkk[b] + bkk[b];          // g_kern (no relu)
        gs[gbase + 9 + b] = fmaxf(acc[b] + bco, 0.f);       // sk (relu)
    }
}

// ---------------------------------------------------------------------------
// Kernel 3: materialize dynW[n][o][c][b] = relu(Wck[o][0]*g + Wck[o][1]*s + bck[o])
// 4,718,592 elements, trivially parallel.
// ---------------------------------------------------------------------------
__global__ __launch_bounds__(256) void dynw_kernel(const float* __restrict__ gs,
                                                   const float* __restrict__ Wck,
                                                   const float* __restrict__ bck,
                                                   float* __restrict__ dynW) {
    int idx = blockIdx.x * 256 + threadIdx.x;   // enumerates (n,o,c,b), b fastest
    int b = idx % 9;
    int c = (idx / 9) % CM_;
    int o = (idx / (9 * CM_)) % CM_;
    int n = idx / (9 * CM_ * CM_);
    float g = gs[((size_t)(n * CM_ + c)) * 18 + b];
    float s = gs[((size_t)(n * CM_ + c)) * 18 + 9 + b];
    float v = Wck[o * 2] * g + Wck[o * 2 + 1] * s + bck[o];
    dynW[idx] = fmaxf(v, 0.f);
}

// ---------------------------------------------------------------------------
// Kernel 4: f = relu(Wc @ x + bc). GEMM M=128(o) K=512(c) per (n, 64-col tile).
// Block 256 threads computes 128x64; per-thread 8x4 accumulators.
// ---------------------------------------------------------------------------
__global__ __launch_bounds__(256) void fconv_kernel(const float* __restrict__ x,
                                                    const float* __restrict__ Wc,
                                                    const float* __restrict__ bc,
                                                    float* __restrict__ f) {
    int n = blockIdx.y;
    int hw0 = blockIdx.x * 64;
    __shared__ float As[16][128];   // [kk][o]
    __shared__ float Bs[16][64];    // [kk][j]
    int t = threadIdx.x;
    int to = t >> 4;                // o base = to*8
    int tj = t & 15;                // j base = tj*4
    float acc[8][4] = {};
    for (int c0 = 0; c0 < C_; c0 += 16) {
        __syncthreads();
        for (int i = t; i < 2048; i += 256) {
            int o = i >> 4, kk = i & 15;
            As[kk][o] = Wc[(size_t)o * C_ + c0 + kk];
        }
        for (int i = t; i < 1024; i += 256) {
            int kk = i >> 6, j = i & 63;
            Bs[kk][j] = x[((size_t)n * C_ + c0 + kk) * HW_ + hw0 + j];
        }
        __syncthreads();
#pragma unroll
        for (int kk = 0; kk < 16; ++kk) {
            float4 a0 = *(const float4*)&As[kk][to * 8];
            float4 a1 = *(const float4*)&As[kk][to * 8 + 4];
            float4 bv = *(const float4*)&Bs[kk][tj * 4];
            float a[8] = {a0.x, a0.y, a0.z, a0.w, a1.x, a1.y, a1.z, a1.w};
            float bb[4] = {bv.x, bv.y, bv.z, bv.w};
#pragma unroll
            for (int i = 0; i < 8; ++i)
#pragma unroll
                for (int rr = 0; rr < 4; ++rr) acc[i][rr] += a[i] * bb[rr];
        }
    }
#pragma unroll
    for (int i = 0; i < 8; ++i) {
        int o = to * 8 + i;
        float bco = bc[o];
#pragma unroll
        for (int rr = 0; rr < 4; ++rr)
            f[((size_t)n * CM_ + o) * HW_ + hw0 + tj * 4 + rr] = fmaxf(acc[i][rr] + bco, 0.f);
    }
}

// ---------------------------------------------------------------------------
// Kernel 5: per-sample dynamic 3x3 conv: y[n,o,h,w] = b_ad[o] +
//   sum_{c,dh,dw} dynW[n,o,c,dh*3+dw] * f[n,c,h+dh-1,w+dw-1]   (zero pad)
// Block: (n, 32-o tile, 8-row tile x full 48 cols). LDS: f halo tile + weights.
// ---------------------------------------------------------------------------
__global__ __launch_bounds__(256) void dynconv_kernel(const float* __restrict__ f,
                                                      const float* __restrict__ dynW,
                                                      const float* __restrict__ b_ad,
                                                      float* __restrict__ y) {
    int n = blockIdx.z;
    int o0 = blockIdx.y * 32;
    int h0 = blockIdx.x * 8;
    __shared__ float fs[4][10][50];     // c-chunk x (8+2) x (48+2)
    __shared__ float ws[32][36];        // [oo][cc*9+r]
    int t = threadIdx.x;
    int to = t >> 5;                    // 0..7 -> o = o0 + to*4 + {0..3}
    int ts = t & 31;                    // spatial: p = ts + 32*i, i in 0..11
    int hh[12], ww[12];
#pragma unroll
    for (int i = 0; i < 12; ++i) {
        int p = ts + 32 * i;
        hh[i] = p / 48;
        ww[i] = p % 48;
    }
    float acc[4][12];
#pragma unroll
    for (int a = 0; a < 4; ++a)
#pragma unroll
        for (int i = 0; i < 12; ++i) acc[a][i] = 0.f;

    for (int c0 = 0; c0 < CM_; c0 += 4) {
        __syncthreads();
        // stage f halo tile (zero-padded)
        for (int i = t; i < 2000; i += 256) {
            int cc = i / 500;
            int rem = i % 500;
            int lh = rem / 50, lw = rem % 50;
            int gh = h0 - 1 + lh, gw = lw - 1;
            float v = 0.f;
            if (gh >= 0 && gh < H_ && gw >= 0 && gw < W_)
                v = f[((size_t)n * CM_ + c0 + cc) * HW_ + gh * W_ + gw];
            fs[cc][lh][lw] = v;
        }
        // stage weights: 32 o x 4 c x 9 (contiguous 36 floats per o)
        for (int i = t; i < 1152; i += 256) {
            int oo = i / 36, rem = i % 36;
            ws[oo][rem] = dynW[(((size_t)n * CM_ + o0 + oo) * CM_ + c0) * 9 + rem];
        }
        __syncthreads();
#pragma unroll
        for (int cc = 0; cc < 4; ++cc) {
            float wreg[4][9];
#pragma unroll
            for (int a = 0; a < 4; ++a)
#pragma unroll
                for (int rr = 0; rr < 9; ++rr) wreg[a][rr] = ws[to * 4 + a][cc * 9 + rr];
#pragma unroll
            for (int i = 0; i < 12; ++i) {
                float fv[9];
#pragma unroll
                for (int dh = 0; dh < 3; ++dh)
#pragma unroll
                    for (int dw = 0; dw < 3; ++dw)
                        fv[dh * 3 + dw] = fs[cc][hh[i] + dh][ww[i] + dw];
#pragma unroll
                for (int a = 0; a < 4; ++a) {
                    float sacc = 0.f;
#pragma unroll
                    for (int rr = 0; rr < 9; ++rr) sacc += wreg[a][rr] * fv[rr];
                    acc[a][i] += sacc;
                }
            }
        }
    }
#pragma unroll
    for (int a = 0; a < 4; ++a) {
        int o = o0 + to * 4 + a;
        float bias = b_ad[o];
#pragma unroll
        for (int i = 0; i < 12; ++i)
            y[((size_t)n * CM_ + o) * HW_ + (h0 + hh[i]) * W_ + ww[i]] = acc[a][i] + bias;
    }
}

// ---------------------------------------------------------------------------
// Kernel 6: out = Wf @ y + bf. GEMM M=512(p) K=128(c), per (n, 64p x 64hw tile).
// ---------------------------------------------------------------------------
__global__ __launch_bounds__(256) void fuse_kernel(const float* __restrict__ y,
                                                   const float* __restrict__ Wf,
                                                   const float* __restrict__ bf,
                                                   float* __restrict__ out) {
    int n = blockIdx.z;
    int p0 = blockIdx.y * 64;
    int hw0 = blockIdx.x * 64;
    __shared__ float As[16][64];
    __shared__ float Bs[16][64];
    int t = threadIdx.x;
    int tp = t >> 4, tj = t & 15;
    float acc[4][4] = {};
    for (int c0 = 0; c0 < CM_; c0 += 16) {
        __syncthreads();
        for (int i = t; i < 1024; i += 256) {
            int pp = i >> 4, kk = i & 15;
            As[kk][pp] = Wf[(size_t)(p0 + pp) * CM_ + c0 + kk];
        }
        for (int i = t; i < 1024; i += 256) {
            int kk = i >> 6, j = i & 63;
            Bs[kk][j] = y[((size_t)n * CM_ + c0 + kk) * HW_ + hw0 + j];
        }
        __syncthreads();
#pragma unroll
        for (int kk = 0; kk < 16; ++kk) {
            float4 av = *(const float4*)&As[kk][tp * 4];
            float4 bv = *(const float4*)&Bs[kk][tj * 4];
            float a[4] = {av.x, av.y, av.z, av.w};
            float bb[4] = {bv.x, bv.y, bv.z, bv.w};
#pragma unroll
            for (int i = 0; i < 4; ++i)
#pragma unroll
                for (int rr = 0; rr < 4; ++rr) acc[i][rr] += a[i] * bb[rr];
        }
    }
#pragma unroll
    for (int i = 0; i < 4; ++i) {
        int p = p0 + tp * 4 + i;
        float bfp = bf[p];
#pragma unroll
        for (int rr = 0; rr < 4; ++rr)
            out[((size_t)n * P_ + p) * HW_ + hw0 + tj * 4 + rr] = acc[i][rr] + bfp;
    }
}

// ---------------------------------------------------------------------------
// Launch. Workspace layout (floats):
//   meanx 16384 | xm 147456 | gs 73728 | dynW 4718592 | f 9437184 | y 9437184
//   total = 23,830,528 floats = 95.3 MB
// ---------------------------------------------------------------------------
extern "C" void kernel_launch(void* const* d_in, const int* in_sizes, int n_in,
                              void* d_out, int out_size, void* d_ws, size_t ws_size,
                              hipStream_t stream) {
    const float* x    = (const float*)d_in[0];
    const float* Wc   = (const float*)d_in[1];
    const float* bc   = (const float*)d_in[2];
    const float* Wkk  = (const float*)d_in[3];
    const float* bkk  = (const float*)d_in[4];
    const float* Wck  = (const float*)d_in[5];
    const float* bck  = (const float*)d_in[6];
    const float* b_ad = (const float*)d_in[7];
    const float* Wf   = (const float*)d_in[8];
    const float* bf   = (const float*)d_in[9];
    float* out = (float*)d_out;

    float* ws    = (float*)d_ws;
    float* meanx = ws;
    float* xm    = meanx + 16384;
    float* gs    = xm + 147456;
    float* dynW  = gs + 73728;
    float* f     = dynW + 4718592;
    float* y     = f + 9437184;

    hipLaunchKernelGGL(pool_kernel,    dim3(N_ * C_), dim3(256), 0, stream, x, meanx, xm);
    hipLaunchKernelGGL(branch_kernel,  dim3(N_),      dim3(128), 0, stream, meanx, xm, Wc, bc, Wkk, bkk, gs);
    hipLaunchKernelGGL(dynw_kernel,    dim3(18432),   dim3(256), 0, stream, gs, Wck, bck, dynW);
    hipLaunchKernelGGL(fconv_kernel,   dim3(36, 32),  dim3(256), 0, stream, x, Wc, bc, f);
    hipLaunchKernelGGL(dynconv_kernel, dim3(6, 4, 32),dim3(256), 0, stream, f, dynW, b_ad, y);
    hipLaunchKernelGGL(fuse_kernel,    dim3(36, 8, 32), dim3(256), 0, stream, y, Wf, bf, out);
}

// Round 2
// 778.027 us; speedup vs baseline: 2.1627x; 2.1627x over previous
//
#include <hip/hip_runtime.h>

// Problem constants (fixed by setup_inputs)
#define N_   32
#define C_   512
#define CM_  128
#define H_   48
#define W_   48
#define HW_  (H_*W_)
#define P_   512

typedef unsigned short ushort_t;
typedef short s8v  __attribute__((ext_vector_type(8)));   // 8 bf16 (4 VGPRs) MFMA A/B frag
typedef float f4v  __attribute__((ext_vector_type(4)));   // 4 fp32 MFMA C/D frag

// fp32 -> bf16 (round to nearest even)
__device__ __forceinline__ ushort_t f2bf(float x) {
    unsigned int u = __float_as_uint(x);
    u += 0x7fffu + ((u >> 16) & 1u);
    return (ushort_t)(u >> 16);
}

// ---------------------------------------------------------------------------
// Kernel 1: per-(n,c) plane: mean over 48x48 and 3x3 adaptive max pool (16x16
// regions). One 256-thread block per plane.
// ---------------------------------------------------------------------------
__global__ __launch_bounds__(256) void pool_kernel(const float* __restrict__ x,
                                                   float* __restrict__ meanx,
                                                   float* __restrict__ xm) {
    int plane = blockIdx.x;                 // n*C + c
    const float* base = x + (size_t)plane * HW_;
    int t = threadIdx.x;
    int r = t >> 4, cc = t & 15;            // position within 16x16 region
    float sum = 0.f;
    float mx[9];
#pragma unroll
    for (int b = 0; b < 9; ++b) {
        int h = (b / 3) * 16 + r;
        int w = (b % 3) * 16 + cc;
        float v = base[h * W_ + w];
        mx[b] = v;
        sum += v;
    }
#pragma unroll
    for (int off = 32; off > 0; off >>= 1) {
        sum += __shfl_down(sum, off);
#pragma unroll
        for (int b = 0; b < 9; ++b) mx[b] = fmaxf(mx[b], __shfl_down(mx[b], off));
    }
    __shared__ float s[4][10];
    int wave = t >> 6, lane = t & 63;
    if (lane == 0) {
#pragma unroll
        for (int b = 0; b < 9; ++b) s[wave][b] = mx[b];
        s[wave][9] = sum;
    }
    __syncthreads();
    if (t < 9) {
        float v = fmaxf(fmaxf(s[0][t], s[1][t]), fmaxf(s[2][t], s[3][t]));
        xm[(size_t)plane * 9 + t] = v;
    } else if (t == 9) {
        float v = s[0][9] + s[1][9] + s[2][9] + s[3][9];
        meanx[plane] = v * (1.0f / (float)HW_);
    }
}

// ---------------------------------------------------------------------------
// Kernel 2: per-sample branch math. Block = one n, 128 threads (one per o).
// gs layout: [n][18][Cm]  (j index: 0..8 = g_kern(b), 9..17 = sk(b); c contig)
// ---------------------------------------------------------------------------
__global__ __launch_bounds__(128) void branch_kernel(const float* __restrict__ meanx,
                                                     const float* __restrict__ xm,
                                                     const float* __restrict__ Wc,
                                                     const float* __restrict__ bc,
                                                     const float* __restrict__ Wkk,
                                                     const float* __restrict__ bkk,
                                                     float* __restrict__ gs) {
    int n = blockIdx.x;
    __shared__ float sin_[C_ * 10];
    int t = threadIdx.x;
    for (int i = t; i < C_ * 10; i += 128) {
        int c = i / 10, j = i % 10;
        sin_[i] = (j < 9) ? xm[((size_t)n * C_ + c) * 9 + j] : meanx[n * C_ + c];
    }
    __syncthreads();
    int o = t;
    float acc[10];
#pragma unroll
    for (int j = 0; j < 10; ++j) acc[j] = 0.f;
    const float* wrow = Wc + (size_t)o * C_;
    for (int c = 0; c < C_; ++c) {
        float wv = wrow[c];
        const float* in = &sin_[c * 10];
#pragma unroll
        for (int j = 0; j < 10; ++j) acc[j] += wv * in[j];
    }
    float bco = bc[o];
    float gk1 = fmaxf(acc[9] + bco, 0.f);
    size_t gbase = (size_t)n * 18 * CM_;
#pragma unroll
    for (int b = 0; b < 9; ++b) {
        gs[gbase + b * CM_ + o]       = gk1 * Wkk[b] + bkk[b];          // g_kern (no relu)
        gs[gbase + (9 + b) * CM_ + o] = fmaxf(acc[b] + bco, 0.f);       // sk (relu)
    }
}

// ---------------------------------------------------------------------------
// Kernel 3: dynW_t[n][r][o][c] (bf16, c contiguous) =
//   relu(Wck[o][0]*g[n,c,r] + Wck[o][1]*s[n,c,r] + bck[o])
// Thread handles 8 consecutive c -> one 16B store.
// idx = (((n*9 + r)*128 + o)*16 + c8)
// ---------------------------------------------------------------------------
__global__ __launch_bounds__(256) void dynw_kernel(const float* __restrict__ gs,
                                                   const float* __restrict__ Wck,
                                                   const float* __restrict__ bck,
                                                   ushort_t* __restrict__ dynW_t) {
    int idx = blockIdx.x * 256 + threadIdx.x;     // 589824 threads
    int c8 = idx & 15;
    int o  = (idx >> 4) & 127;
    int v  = idx >> 11;                           // n*9 + r
    int r  = v % 9;
    int n  = v / 9;
    const float* gp = gs + ((size_t)n * 18 + r) * CM_ + c8 * 8;
    float w0 = Wck[o * 2], w1 = Wck[o * 2 + 1], bk = bck[o];
    ushort_t u[8];
#pragma unroll
    for (int i = 0; i < 8; ++i) {
        float g = gp[i];
        float s = gp[9 * CM_ + i];
        u[i] = f2bf(fmaxf(w0 * g + w1 * s + bk, 0.f));
    }
    uint4 pk;
    pk.x = (unsigned)u[0] | ((unsigned)u[1] << 16);
    pk.y = (unsigned)u[2] | ((unsigned)u[3] << 16);
    pk.z = (unsigned)u[4] | ((unsigned)u[5] << 16);
    pk.w = (unsigned)u[6] | ((unsigned)u[7] << 16);
    *(uint4*)(dynW_t + (size_t)idx * 8) = pk;
}

// ---------------------------------------------------------------------------
// Kernel 4: f = relu(Wc @ x + bc), written as bf16 channels-last:
//   f_t[n][h][w][c]  (c=128 contiguous).  GEMM M=128(o) K=512(c) per
//   (n, 64-hw tile); fp32 compute in registers; epilogue packs 8 bf16 / 16B.
// ---------------------------------------------------------------------------
__global__ __launch_bounds__(256) void fconv_kernel(const float* __restrict__ x,
                                                    const float* __restrict__ Wc,
                                                    const float* __restrict__ bc,
                                                    ushort_t* __restrict__ f_t) {
    int n = blockIdx.y;
    int hw0 = blockIdx.x * 64;
    __shared__ float As[16][128];   // [kk][o]
    __shared__ float Bs[16][64];    // [kk][j]
    int t = threadIdx.x;
    int to = t >> 4;                // o base = to*8
    int tj = t & 15;                // hw base = tj*4
    float acc[8][4] = {};
    for (int c0 = 0; c0 < C_; c0 += 16) {
        __syncthreads();
        for (int i = t; i < 2048; i += 256) {
            int o = i >> 4, kk = i & 15;
            As[kk][o] = Wc[(size_t)o * C_ + c0 + kk];
        }
        for (int i = t; i < 1024; i += 256) {
            int kk = i >> 6, j = i & 63;
            Bs[kk][j] = x[((size_t)n * C_ + c0 + kk) * HW_ + hw0 + j];
        }
        __syncthreads();
#pragma unroll
        for (int kk = 0; kk < 16; ++kk) {
            float4 a0 = *(const float4*)&As[kk][to * 8];
            float4 a1 = *(const float4*)&As[kk][to * 8 + 4];
            float4 bv = *(const float4*)&Bs[kk][tj * 4];
            float a[8] = {a0.x, a0.y, a0.z, a0.w, a1.x, a1.y, a1.z, a1.w};
            float bb[4] = {bv.x, bv.y, bv.z, bv.w};
#pragma unroll
            for (int i = 0; i < 8; ++i)
#pragma unroll
                for (int rr = 0; rr < 4; ++rr) acc[i][rr] += a[i] * bb[rr];
        }
    }
    // epilogue: relu + bf16, f_t[(n*2304 + hw)*128 + o], 8 o's per 16B store
#pragma unroll
    for (int rr = 0; rr < 4; ++rr) {
        int hw = hw0 + tj * 4 + rr;
        ushort_t u[8];
#pragma unroll
        for (int i = 0; i < 8; ++i) {
            int o = to * 8 + i;
            u[i] = f2bf(fmaxf(acc[i][rr] + bc[o], 0.f));
        }
        uint4 pk;
        pk.x = (unsigned)u[0] | ((unsigned)u[1] << 16);
        pk.y = (unsigned)u[2] | ((unsigned)u[3] << 16);
        pk.z = (unsigned)u[4] | ((unsigned)u[5] << 16);
        pk.w = (unsigned)u[6] | ((unsigned)u[7] << 16);
        *(uint4*)(f_t + ((size_t)n * HW_ + hw) * CM_ + to * 8) = pk;
    }
}

// ---------------------------------------------------------------------------
// Kernel 5: dynamic 3x3 conv via MFMA bf16, no LDS.
//   y[n,o,h,w] = b_ad[o] + sum_{c,r} dynW[n,o,c,r] * f[n,c,(h,w)+shift(r)]
// GEMM per sample: M=o(128), N=hw(2304), K=c(128) accumulated over 9 shifts.
// Block = 128 thr (2 waves): o-half (64) x 4 rows x 48 w. Wave = 64o x 2rows.
// A-frag: dynW_t[n][r][o0+mt*16+j][cc*32 + q*8 ..+7]      (16B global load)
// B-frag: f_t[n][h+dh][w+dw][cc*32 + q*8 ..+7]            (16B global load)
// D-frag: col j = w offset, row q*4+reg = o offset within 16-tile.
// ---------------------------------------------------------------------------
__global__ __launch_bounds__(128) void dynconv_mfma(const ushort_t* __restrict__ f_t,
                                                    const ushort_t* __restrict__ dynW_t,
                                                    const float* __restrict__ b_ad,
                                                    float* __restrict__ y) {
    int n  = blockIdx.z;
    int o0 = blockIdx.y * 64;
    int h0 = blockIdx.x * 4;
    int t = threadIdx.x;
    int wave = t >> 6, lane = t & 63;
    int j = lane & 15, q = lane >> 4;
    int rbase = h0 + wave * 2;            // this wave's 2 rows

    const s8v* A = (const s8v*)dynW_t;    // s8v units: 16 bytes = 8 bf16
    const s8v* B = (const s8v*)f_t;
    // A index: ((n*9+r)*128 + o)*16 + (cc*4 + q)
    size_t abase = (((size_t)n * 9) * 128 + o0 + j) * 16 + q;

    f4v acc[4][6];
#pragma unroll
    for (int mt = 0; mt < 4; ++mt)
#pragma unroll
        for (int nt = 0; nt < 6; ++nt) acc[mt][nt] = (f4v){0.f, 0.f, 0.f, 0.f};
    const s8v zero = (s8v)0;

    for (int cc = 0; cc < 4; ++cc) {
        for (int r = 0; r < 9; ++r) {
            int dh = r / 3 - 1, dw = r % 3 - 1;
            s8v a[4];
#pragma unroll
            for (int mt = 0; mt < 4; ++mt)
                a[mt] = A[abase + (size_t)r * 2048 + mt * 256 + cc * 4];
            s8v b[6];
#pragma unroll
            for (int rl = 0; rl < 2; ++rl) {
                int h = rbase + rl + dh;
                bool hok = (unsigned)h < (unsigned)H_;
#pragma unroll
                for (int wg = 0; wg < 3; ++wg) {
                    int w = wg * 16 + j + dw;
                    s8v v = zero;
                    if (hok && (unsigned)w < (unsigned)W_)
                        v = B[((size_t)n * HW_ + h * W_ + w) * 16 + q + cc * 4];
                    b[rl * 3 + wg] = v;
                }
            }
#pragma unroll
            for (int mt = 0; mt < 4; ++mt)
#pragma unroll
                for (int nt = 0; nt < 6; ++nt)
                    acc[mt][nt] = __builtin_amdgcn_mfma_f32_16x16x32_bf16(
                        a[mt], b[nt], acc[mt][nt], 0, 0, 0);
        }
    }
    // epilogue: y fp32 [n][o][h][w]
#pragma unroll
    for (int mt = 0; mt < 4; ++mt) {
        float ba[4];
#pragma unroll
        for (int reg = 0; reg < 4; ++reg)
            ba[reg] = b_ad[o0 + mt * 16 + q * 4 + reg];
#pragma unroll
        for (int rl = 0; rl < 2; ++rl) {
            int h = rbase + rl;
#pragma unroll
            for (int wg = 0; wg < 3; ++wg) {
                int nt = rl * 3 + wg;
#pragma unroll
                for (int reg = 0; reg < 4; ++reg) {
                    int o = o0 + mt * 16 + q * 4 + reg;
                    y[((size_t)n * CM_ + o) * HW_ + h * W_ + wg * 16 + j] =
                        acc[mt][nt][reg] + ba[reg];
                }
            }
        }
    }
}

// ---------------------------------------------------------------------------
// Kernel 6: out = Wf @ y + bf. GEMM M=512(p) K=128(c), per (n, 64p x 64hw tile).
// ---------------------------------------------------------------------------
__global__ __launch_bounds__(256) void fuse_kernel(const float* __restrict__ y,
                                                   const float* __restrict__ Wf,
                                                   const float* __restrict__ bf,
                                                   float* __restrict__ out) {
    int n = blockIdx.z;
    int p0 = blockIdx.y * 64;
    int hw0 = blockIdx.x * 64;
    __shared__ float As[16][64];
    __shared__ float Bs[16][64];
    int t = threadIdx.x;
    int tp = t >> 4, tj = t & 15;
    float acc[4][4] = {};
    for (int c0 = 0; c0 < CM_; c0 += 16) {
        __syncthreads();
        for (int i = t; i < 1024; i += 256) {
            int pp = i >> 4, kk = i & 15;
            As[kk][pp] = Wf[(size_t)(p0 + pp) * CM_ + c0 + kk];
        }
        for (int i = t; i < 1024; i += 256) {
            int kk = i >> 6, jv = i & 63;
            Bs[kk][jv] = y[((size_t)n * CM_ + c0 + kk) * HW_ + hw0 + jv];
        }
        __syncthreads();
#pragma unroll
        for (int kk = 0; kk < 16; ++kk) {
            float4 av = *(const float4*)&As[kk][tp * 4];
            float4 bv = *(const float4*)&Bs[kk][tj * 4];
            float a[4] = {av.x, av.y, av.z, av.w};
            float bb[4] = {bv.x, bv.y, bv.z, bv.w};
#pragma unroll
            for (int i = 0; i < 4; ++i)
#pragma unroll
                for (int rr = 0; rr < 4; ++rr) acc[i][rr] += a[i] * bb[rr];
        }
    }
#pragma unroll
    for (int i = 0; i < 4; ++i) {
        int p = p0 + tp * 4 + i;
        float bfp = bf[p];
#pragma unroll
        for (int rr = 0; rr < 4; ++rr)
            out[((size_t)n * P_ + p) * HW_ + hw0 + tj * 4 + rr] = acc[i][rr] + bfp;
    }
}

// ---------------------------------------------------------------------------
// Launch. Workspace layout (bytes):
//   meanx f32 @0 (65536) | xm f32 @65536 (589824) | gs f32 @655360 (294912)
//   dynW_t bf16 @950272 (9437184) | f_t bf16 @10387456 (18874368)
//   y f32 @29261824 (37748736)  -> total ~67 MB
// ---------------------------------------------------------------------------
extern "C" void kernel_launch(void* const* d_in, const int* in_sizes, int n_in,
                              void* d_out, int out_size, void* d_ws, size_t ws_size,
                              hipStream_t stream) {
    const float* x    = (const float*)d_in[0];
    const float* Wc   = (const float*)d_in[1];
    const float* bc   = (const float*)d_in[2];
    const float* Wkk  = (const float*)d_in[3];
    const float* bkk  = (const float*)d_in[4];
    const float* Wck  = (const float*)d_in[5];
    const float* bck  = (const float*)d_in[6];
    const float* b_ad = (const float*)d_in[7];
    const float* Wf   = (const float*)d_in[8];
    const float* bf   = (const float*)d_in[9];
    float* out = (float*)d_out;

    char* ws = (char*)d_ws;
    float*    meanx  = (float*)(ws);
    float*    xm     = (float*)(ws + 65536);
    float*    gs     = (float*)(ws + 655360);
    ushort_t* dynW_t = (ushort_t*)(ws + 950272);
    ushort_t* f_t    = (ushort_t*)(ws + 10387456);
    float*    y      = (float*)(ws + 29261824);

    hipLaunchKernelGGL(pool_kernel,    dim3(N_ * C_), dim3(256), 0, stream, x, meanx, xm);
    hipLaunchKernelGGL(branch_kernel,  dim3(N_),      dim3(128), 0, stream, meanx, xm, Wc, bc, Wkk, bkk, gs);
    hipLaunchKernelGGL(dynw_kernel,    dim3(2304),    dim3(256), 0, stream, gs, Wck, bck, dynW_t);
    hipLaunchKernelGGL(fconv_kernel,   dim3(36, 32),  dim3(256), 0, stream, x, Wc, bc, f_t);
    hipLaunchKernelGGL(dynconv_mfma,   dim3(12, 2, 32), dim3(128), 0, stream, f_t, dynW_t, b_ad, y);
    hipLaunchKernelGGL(fuse_kernel,    dim3(36, 8, 32), dim3(256), 0, stream, y, Wf, bf, out);
}

// Round 3
// 456.215 us; speedup vs baseline: 3.6882x; 1.7054x over previous
//
#include <hip/hip_runtime.h>

// Problem constants (fixed by setup_inputs)
#define N_   32
#define C_   512
#define CM_  128
#define H_   48
#define W_   48
#define HW_  (H_*W_)
#define P_   512

typedef unsigned short ushort_t;
typedef short s8v  __attribute__((ext_vector_type(8)));   // 8 bf16 (4 VGPRs) MFMA A/B frag
typedef float f4v  __attribute__((ext_vector_type(4)));   // 4 fp32 MFMA C/D frag

// fp32 -> bf16 (round to nearest even)
__device__ __forceinline__ ushort_t f2bf(float x) {
    unsigned int u = __float_as_uint(x);
    u += 0x7fffu + ((u >> 16) & 1u);
    return (ushort_t)(u >> 16);
}

// ---------------------------------------------------------------------------
// Kernel 1: per-(n,c) plane: mean over 48x48 and 3x3 adaptive max pool (16x16
// regions). One 256-thread block per plane.
// ---------------------------------------------------------------------------
__global__ __launch_bounds__(256) void pool_kernel(const float* __restrict__ x,
                                                   float* __restrict__ meanx,
                                                   float* __restrict__ xm) {
    int plane = blockIdx.x;                 // n*C + c
    const float* base = x + (size_t)plane * HW_;
    int t = threadIdx.x;
    int r = t >> 4, cc = t & 15;            // position within 16x16 region
    float sum = 0.f;
    float mx[9];
#pragma unroll
    for (int b = 0; b < 9; ++b) {
        int h = (b / 3) * 16 + r;
        int w = (b % 3) * 16 + cc;
        float v = base[h * W_ + w];
        mx[b] = v;
        sum += v;
    }
#pragma unroll
    for (int off = 32; off > 0; off >>= 1) {
        sum += __shfl_down(sum, off);
#pragma unroll
        for (int b = 0; b < 9; ++b) mx[b] = fmaxf(mx[b], __shfl_down(mx[b], off));
    }
    __shared__ float s[4][10];
    int wave = t >> 6, lane = t & 63;
    if (lane == 0) {
#pragma unroll
        for (int b = 0; b < 9; ++b) s[wave][b] = mx[b];
        s[wave][9] = sum;
    }
    __syncthreads();
    if (t < 9) {
        float v = fmaxf(fmaxf(s[0][t], s[1][t]), fmaxf(s[2][t], s[3][t]));
        xm[(size_t)plane * 9 + t] = v;
    } else if (t == 9) {
        float v = s[0][9] + s[1][9] + s[2][9] + s[3][9];
        meanx[plane] = v * (1.0f / (float)HW_);
    }
}

// ---------------------------------------------------------------------------
// Kernel 2: per-sample branch math. gs layout: [n][18][Cm] (c contiguous).
// ---------------------------------------------------------------------------
__global__ __launch_bounds__(128) void branch_kernel(const float* __restrict__ meanx,
                                                     const float* __restrict__ xm,
                                                     const float* __restrict__ Wc,
                                                     const float* __restrict__ bc,
                                                     const float* __restrict__ Wkk,
                                                     const float* __restrict__ bkk,
                                                     float* __restrict__ gs) {
    int n = blockIdx.x;
    __shared__ float sin_[C_ * 10];
    int t = threadIdx.x;
    for (int i = t; i < C_ * 10; i += 128) {
        int c = i / 10, j = i % 10;
        sin_[i] = (j < 9) ? xm[((size_t)n * C_ + c) * 9 + j] : meanx[n * C_ + c];
    }
    __syncthreads();
    int o = t;
    float acc[10];
#pragma unroll
    for (int j = 0; j < 10; ++j) acc[j] = 0.f;
    const float* wrow = Wc + (size_t)o * C_;
    for (int c = 0; c < C_; ++c) {
        float wv = wrow[c];
        const float* in = &sin_[c * 10];
#pragma unroll
        for (int j = 0; j < 10; ++j) acc[j] += wv * in[j];
    }
    float bco = bc[o];
    float gk1 = fmaxf(acc[9] + bco, 0.f);
    size_t gbase = (size_t)n * 18 * CM_;
#pragma unroll
    for (int b = 0; b < 9; ++b) {
        gs[gbase + b * CM_ + o]       = gk1 * Wkk[b] + bkk[b];          // g_kern (no relu)
        gs[gbase + (9 + b) * CM_ + o] = fmaxf(acc[b] + bco, 0.f);       // sk (relu)
    }
}

// ---------------------------------------------------------------------------
// Kernel 3: dynW_t[n][r][o][c] (bf16, c contiguous).
// ---------------------------------------------------------------------------
__global__ __launch_bounds__(256) void dynw_kernel(const float* __restrict__ gs,
                                                   const float* __restrict__ Wck,
                                                   const float* __restrict__ bck,
                                                   ushort_t* __restrict__ dynW_t) {
    int idx = blockIdx.x * 256 + threadIdx.x;     // 589824 threads
    int c8 = idx & 15;
    int o  = (idx >> 4) & 127;
    int v  = idx >> 11;                           // n*9 + r
    int r  = v % 9;
    int n  = v / 9;
    const float* gp = gs + ((size_t)n * 18 + r) * CM_ + c8 * 8;
    float w0 = Wck[o * 2], w1 = Wck[o * 2 + 1], bk = bck[o];
    ushort_t u[8];
#pragma unroll
    for (int i = 0; i < 8; ++i) {
        float g = gp[i];
        float s = gp[9 * CM_ + i];
        u[i] = f2bf(fmaxf(w0 * g + w1 * s + bk, 0.f));
    }
    uint4 pk;
    pk.x = (unsigned)u[0] | ((unsigned)u[1] << 16);
    pk.y = (unsigned)u[2] | ((unsigned)u[3] << 16);
    pk.z = (unsigned)u[4] | ((unsigned)u[5] << 16);
    pk.w = (unsigned)u[6] | ((unsigned)u[7] << 16);
    *(uint4*)(dynW_t + (size_t)idx * 8) = pk;
}

// ---------------------------------------------------------------------------
// Kernel 3b: cast Wc (65536) and Wf (65536) to bf16, row-major unchanged.
// 4 elements per thread; 192 blocks x 256.
// ---------------------------------------------------------------------------
__global__ __launch_bounds__(256) void convw_kernel(const float* __restrict__ Wc,
                                                    const float* __restrict__ Wf,
                                                    ushort_t* __restrict__ Wc_bf,
                                                    ushort_t* __restrict__ Wf_bf) {
    int idx = blockIdx.x * 256 + threadIdx.x;     // 49152 threads x 4 elems
    float4 v;
    ushort_t* dst;
    if (idx < 16384) {
        v = ((const float4*)Wc)[idx];
        dst = Wc_bf + (size_t)idx * 4;
    } else {
        int k = idx - 16384;
        v = ((const float4*)Wf)[k];
        dst = Wf_bf + (size_t)k * 4;
    }
    uint2 pk;
    pk.x = (unsigned)f2bf(v.x) | ((unsigned)f2bf(v.y) << 16);
    pk.y = (unsigned)f2bf(v.z) | ((unsigned)f2bf(v.w) << 16);
    *(uint2*)dst = pk;
}

// ---------------------------------------------------------------------------
// Kernel 4: f = relu(Wc @ x + bc) via bf16 MFMA, output channels-last bf16
//   f_t[n][hw][o].  Block 256 thr (4 waves) = 128 o x 64 hw tile, K=512 in
//   chunks of 32. B staged through LDS with fp32->bf16 transpose; A-frags
//   read directly from L2-resident Wc_bf.
// ---------------------------------------------------------------------------
__global__ __launch_bounds__(256) void fconv_mfma(const float* __restrict__ x,
                                                  const ushort_t* __restrict__ Wc_bf,
                                                  const float* __restrict__ bc,
                                                  ushort_t* __restrict__ f_t) {
    int n = blockIdx.y;
    int hw0 = blockIdx.x * 64;
    __shared__ ushort_t Bs[64 * 40];    // [hw][c] rows of 32 c, stride 40 (80B, 16B-aligned)
    int t = threadIdx.x;
    int wave = t >> 6, lane = t & 63;
    int j = lane & 15, q = lane >> 4;
    int o_w = wave * 32;
    int sk  = t >> 4;                   // c-pair 0..15
    int shw = (t & 15) * 4;             // hw 0..60

    const s8v* A = (const s8v*)Wc_bf;   // elem addr o*512 + k -> /8 = o*64 + k/8
    f4v acc[2][4];
#pragma unroll
    for (int mt = 0; mt < 2; ++mt)
#pragma unroll
        for (int nt = 0; nt < 4; ++nt) acc[mt][nt] = (f4v){0.f, 0.f, 0.f, 0.f};

    for (int c0 = 0; c0 < C_; c0 += 32) {
        // global loads first (prefetch before barrier)
        const float* xr = x + ((size_t)n * C_ + c0 + 2 * sk) * HW_ + hw0 + shw;
        float4 v0 = *(const float4*)xr;
        float4 v1 = *(const float4*)(xr + HW_);
        __syncthreads();                // previous iter's frag reads done
        unsigned* Bw = (unsigned*)Bs;
        {
            unsigned w0 = (unsigned)f2bf(v0.x) | ((unsigned)f2bf(v1.x) << 16);
            unsigned w1 = (unsigned)f2bf(v0.y) | ((unsigned)f2bf(v1.y) << 16);
            unsigned w2 = (unsigned)f2bf(v0.z) | ((unsigned)f2bf(v1.z) << 16);
            unsigned w3 = (unsigned)f2bf(v0.w) | ((unsigned)f2bf(v1.w) << 16);
            Bw[(shw + 0) * 20 + sk] = w0;
            Bw[(shw + 1) * 20 + sk] = w1;
            Bw[(shw + 2) * 20 + sk] = w2;
            Bw[(shw + 3) * 20 + sk] = w3;
        }
        __syncthreads();
        s8v a0 = A[(size_t)(o_w + j) * 64 + (c0 >> 3) + q];
        s8v a1 = A[(size_t)(o_w + 16 + j) * 64 + (c0 >> 3) + q];
        s8v b[4];
#pragma unroll
        for (int nt = 0; nt < 4; ++nt)
            b[nt] = *(const s8v*)&Bs[(nt * 16 + j) * 40 + q * 8];
#pragma unroll
        for (int nt = 0; nt < 4; ++nt) {
            acc[0][nt] = __builtin_amdgcn_mfma_f32_16x16x32_bf16(a0, b[nt], acc[0][nt], 0, 0, 0);
            acc[1][nt] = __builtin_amdgcn_mfma_f32_16x16x32_bf16(a1, b[nt], acc[1][nt], 0, 0, 0);
        }
    }
    // epilogue: relu+bias, pack 4 consecutive o (q*4+reg) -> 8B store
#pragma unroll
    for (int mt = 0; mt < 2; ++mt) {
        int ob = o_w + mt * 16 + q * 4;
        float b4[4];
#pragma unroll
        for (int reg = 0; reg < 4; ++reg) b4[reg] = bc[ob + reg];
#pragma unroll
        for (int nt = 0; nt < 4; ++nt) {
            int hw = hw0 + nt * 16 + j;
            ushort_t u[4];
#pragma unroll
            for (int reg = 0; reg < 4; ++reg)
                u[reg] = f2bf(fmaxf(acc[mt][nt][reg] + b4[reg], 0.f));
            uint2 pk;
            pk.x = (unsigned)u[0] | ((unsigned)u[1] << 16);
            pk.y = (unsigned)u[2] | ((unsigned)u[3] << 16);
            *(uint2*)(f_t + ((size_t)n * HW_ + hw) * CM_ + ob) = pk;
        }
    }
}

// ---------------------------------------------------------------------------
// Kernel 5: dynamic 3x3 conv via MFMA bf16, no LDS. Output y_bf[n][hw][o] bf16.
// ---------------------------------------------------------------------------
__global__ __launch_bounds__(128) void dynconv_mfma(const ushort_t* __restrict__ f_t,
                                                    const ushort_t* __restrict__ dynW_t,
                                                    const float* __restrict__ b_ad,
                                                    ushort_t* __restrict__ y_bf) {
    int n  = blockIdx.z;
    int o0 = blockIdx.y * 64;
    int h0 = blockIdx.x * 4;
    int t = threadIdx.x;
    int wave = t >> 6, lane = t & 63;
    int j = lane & 15, q = lane >> 4;
    int rbase = h0 + wave * 2;            // this wave's 2 rows

    const s8v* A = (const s8v*)dynW_t;
    const s8v* B = (const s8v*)f_t;
    size_t abase = (((size_t)n * 9) * 128 + o0 + j) * 16 + q;

    f4v acc[4][6];
#pragma unroll
    for (int mt = 0; mt < 4; ++mt)
#pragma unroll
        for (int nt = 0; nt < 6; ++nt) acc[mt][nt] = (f4v){0.f, 0.f, 0.f, 0.f};
    const s8v zero = (s8v)0;

    for (int cc = 0; cc < 4; ++cc) {
        for (int r = 0; r < 9; ++r) {
            int dh = r / 3 - 1, dw = r % 3 - 1;
            s8v a[4];
#pragma unroll
            for (int mt = 0; mt < 4; ++mt)
                a[mt] = A[abase + (size_t)r * 2048 + mt * 256 + cc * 4];
            s8v b[6];
#pragma unroll
            for (int rl = 0; rl < 2; ++rl) {
                int h = rbase + rl + dh;
                bool hok = (unsigned)h < (unsigned)H_;
#pragma unroll
                for (int wg = 0; wg < 3; ++wg) {
                    int w = wg * 16 + j + dw;
                    s8v v = zero;
                    if (hok && (unsigned)w < (unsigned)W_)
                        v = B[((size_t)n * HW_ + h * W_ + w) * 16 + q + cc * 4];
                    b[rl * 3 + wg] = v;
                }
            }
#pragma unroll
            for (int mt = 0; mt < 4; ++mt)
#pragma unroll
                for (int nt = 0; nt < 6; ++nt)
                    acc[mt][nt] = __builtin_amdgcn_mfma_f32_16x16x32_bf16(
                        a[mt], b[nt], acc[mt][nt], 0, 0, 0);
        }
    }
    // epilogue: y_bf[n][hw][o] bf16, 4 consecutive o per lane -> 8B store
#pragma unroll
    for (int mt = 0; mt < 4; ++mt) {
        int ob = o0 + mt * 16 + q * 4;
        float ba[4];
#pragma unroll
        for (int reg = 0; reg < 4; ++reg) ba[reg] = b_ad[ob + reg];
#pragma unroll
        for (int rl = 0; rl < 2; ++rl) {
            int h = rbase + rl;
#pragma unroll
            for (int wg = 0; wg < 3; ++wg) {
                int nt = rl * 3 + wg;
                int hw = h * W_ + wg * 16 + j;
                ushort_t u[4];
#pragma unroll
                for (int reg = 0; reg < 4; ++reg)
                    u[reg] = f2bf(acc[mt][nt][reg] + ba[reg]);
                uint2 pk;
                pk.x = (unsigned)u[0] | ((unsigned)u[1] << 16);
                pk.y = (unsigned)u[2] | ((unsigned)u[3] << 16);
                *(uint2*)(y_bf + ((size_t)n * HW_ + hw) * CM_ + ob) = pk;
            }
        }
    }
}

// ---------------------------------------------------------------------------
// Kernel 6: out = Wf @ y + bf via bf16 MFMA, no LDS (A from Wf_bf, B from
// y_bf channels-last). Block 128 thr (2 waves) = 64 p x (4 rows x 48 w).
// ---------------------------------------------------------------------------
__global__ __launch_bounds__(128) void fuse_mfma(const ushort_t* __restrict__ y_bf,
                                                 const ushort_t* __restrict__ Wf_bf,
                                                 const float* __restrict__ bf,
                                                 float* __restrict__ out) {
    int n  = blockIdx.z;
    int p0 = blockIdx.y * 64;
    int h0 = blockIdx.x * 4;
    int t = threadIdx.x;
    int wave = t >> 6, lane = t & 63;
    int j = lane & 15, q = lane >> 4;
    int rbase = h0 + wave * 2;

    const s8v* A = (const s8v*)Wf_bf;   // elem p*128 + k -> /8 = p*16 + k/8
    const s8v* B = (const s8v*)y_bf;

    f4v acc[4][6];
#pragma unroll
    for (int mt = 0; mt < 4; ++mt)
#pragma unroll
        for (int nt = 0; nt < 6; ++nt) acc[mt][nt] = (f4v){0.f, 0.f, 0.f, 0.f};

#pragma unroll
    for (int cc = 0; cc < 4; ++cc) {
        s8v a[4];
#pragma unroll
        for (int mt = 0; mt < 4; ++mt)
            a[mt] = A[(size_t)(p0 + mt * 16 + j) * 16 + cc * 4 + q];
        s8v b[6];
#pragma unroll
        for (int rl = 0; rl < 2; ++rl) {
            int h = rbase + rl;
#pragma unroll
            for (int wg = 0; wg < 3; ++wg) {
                int hw = h * W_ + wg * 16 + j;
                b[rl * 3 + wg] = B[((size_t)n * HW_ + hw) * 16 + cc * 4 + q];
            }
        }
#pragma unroll
        for (int mt = 0; mt < 4; ++mt)
#pragma unroll
            for (int nt = 0; nt < 6; ++nt)
                acc[mt][nt] = __builtin_amdgcn_mfma_f32_16x16x32_bf16(
                    a[mt], b[nt], acc[mt][nt], 0, 0, 0);
    }
    // epilogue: out[n][p][hw] fp32
#pragma unroll
    for (int mt = 0; mt < 4; ++mt) {
        int pb = p0 + mt * 16 + q * 4;
        float b4[4];
#pragma unroll
        for (int reg = 0; reg < 4; ++reg) b4[reg] = bf[pb + reg];
#pragma unroll
        for (int rl = 0; rl < 2; ++rl) {
            int h = rbase + rl;
#pragma unroll
            for (int wg = 0; wg < 3; ++wg) {
                int nt = rl * 3 + wg;
                int hw = h * W_ + wg * 16 + j;
#pragma unroll
                for (int reg = 0; reg < 4; ++reg)
                    out[((size_t)n * P_ + pb + reg) * HW_ + hw] = acc[mt][nt][reg] + b4[reg];
            }
        }
    }
}

// ---------------------------------------------------------------------------
// Launch. Workspace layout (bytes):
//   meanx f32 @0 (65536) | xm f32 @65536 (589824) | gs f32 @655360 (294912)
//   dynW_t bf16 @950272 (9437184) | f_t bf16 @10387456 (18874368)
//   y_bf bf16 @29261824 (18874368) | Wc_bf @48136192 (131072)
//   Wf_bf @48267264 (131072)  -> total ~46.2 MB
// ---------------------------------------------------------------------------
extern "C" void kernel_launch(void* const* d_in, const int* in_sizes, int n_in,
                              void* d_out, int out_size, void* d_ws, size_t ws_size,
                              hipStream_t stream) {
    const float* x    = (const float*)d_in[0];
    const float* Wc   = (const float*)d_in[1];
    const float* bc   = (const float*)d_in[2];
    const float* Wkk  = (const float*)d_in[3];
    const float* bkk  = (const float*)d_in[4];
    const float* Wck  = (const float*)d_in[5];
    const float* bck  = (const float*)d_in[6];
    const float* b_ad = (const float*)d_in[7];
    const float* Wf   = (const float*)d_in[8];
    const float* bf   = (const float*)d_in[9];
    float* out = (float*)d_out;

    char* ws = (char*)d_ws;
    float*    meanx  = (float*)(ws);
    float*    xm     = (float*)(ws + 65536);
    float*    gs     = (float*)(ws + 655360);
    ushort_t* dynW_t = (ushort_t*)(ws + 950272);
    ushort_t* f_t    = (ushort_t*)(ws + 10387456);
    ushort_t* y_bf   = (ushort_t*)(ws + 29261824);
    ushort_t* Wc_bf  = (ushort_t*)(ws + 48136192);
    ushort_t* Wf_bf  = (ushort_t*)(ws + 48267264);

    hipLaunchKernelGGL(pool_kernel,    dim3(N_ * C_), dim3(256), 0, stream, x, meanx, xm);
    hipLaunchKernelGGL(branch_kernel,  dim3(N_),      dim3(128), 0, stream, meanx, xm, Wc, bc, Wkk, bkk, gs);
    hipLaunchKernelGGL(dynw_kernel,    dim3(2304),    dim3(256), 0, stream, gs, Wck, bck, dynW_t);
    hipLaunchKernelGGL(convw_kernel,   dim3(128),     dim3(256), 0, stream, Wc, Wf, Wc_bf, Wf_bf);
    hipLaunchKernelGGL(fconv_mfma,     dim3(36, 32),  dim3(256), 0, stream, x, Wc_bf, bc, f_t);
    hipLaunchKernelGGL(dynconv_mfma,   dim3(12, 2, 32), dim3(128), 0, stream, f_t, dynW_t, b_ad, y_bf);
    hipLaunchKernelGGL(fuse_mfma,      dim3(12, 8, 32), dim3(128), 0, stream, y_bf, Wf_bf, bf, out);
}